// Round 13
// baseline (494.158 us; speedup 1.0000x reference)
//
#include <hip/hip_runtime.h>

#define B_ 4
#define T_ 1024
#define C_ 1024
#define H_ 16
#define HD_ 64
#define DFF_ 4096
#define M_ (B_*T_)

typedef __bf16 bf16x8 __attribute__((ext_vector_type(8)));
typedef float floatx4 __attribute__((ext_vector_type(4)));

__device__ __forceinline__ unsigned short f2bf(float f) {
  unsigned int x = __float_as_uint(f);
  x += 0x7fffu + ((x >> 16) & 1u);   // round-to-nearest-even
  return (unsigned short)(x >> 16);
}

__device__ __forceinline__ float exp2_raw(float x) {
  float r; asm("v_exp_f32 %0, %1" : "=v"(r) : "v"(x)); return r;
}

__device__ __forceinline__ void gload16(const void* g, void* l) {
  __builtin_amdgcn_global_load_lds(
      (const __attribute__((address_space(1))) unsigned int*)g,
      (__attribute__((address_space(3))) unsigned int*)l, 16, 0, 0);
}

// ---------- fp32 -> bf16 elementwise (4 elems/thread) ----------
__global__ __launch_bounds__(256)
void conv_f2b(const float* __restrict__ in, unsigned short* __restrict__ out) {
  const size_t i = ((size_t)blockIdx.x * 256 + threadIdx.x) * 4;
  float4 v = *(const float4*)(in + i);
  ushort4 o; o.x = f2bf(v.x); o.y = f2bf(v.y); o.z = f2bf(v.z); o.w = f2bf(v.w);
  *(ushort4*)(out + i) = o;
}

// ---------- W[K][N] fp32 -> Wt[N][K] bf16 (32x32 LDS tile) ----------
__global__ __launch_bounds__(256)
void transpose_conv(const float* __restrict__ W, unsigned short* __restrict__ Wt,
                    int K, int N) {
  __shared__ float Ts[32][33];
  const int t = threadIdx.x;
  const int bn = blockIdx.x * 32, bk = blockIdx.y * 32;
  const int r = t >> 5, c = t & 31;
  #pragma unroll
  for (int i = 0; i < 4; i++)
    Ts[r + i * 8][c] = W[(size_t)(bk + r + i * 8) * N + bn + c];
  __syncthreads();
  #pragma unroll
  for (int i = 0; i < 4; i++)
    Wt[(size_t)(bn + r + i * 8) * K + bk + c] = f2bf(Ts[c][r + i * 8]);
}

// ---------- bf16 MFMA GEMM: out = A @ Wt^T + bias (+res) ----------
// A: [M][K] bf16.  Wt: [N][K] bf16.  Tile TM x 128, BK=64.
// TM=128: 256 thr / 4 waves, single-buffered (m97 structure). Needs >=2
// blocks/CU; measured 604-631 TF on M=N>=1024-tile shapes at K>=1024.
// TM=64 : 128 thr / 2 waves, double-buffered LDS (s_barrier + vmcnt(12)):
// measured-best for skinny M=4096/N=1024/K=1024 (287 TF; TM=128 1 blk/CU
// and TM=128 split-K=2 both measured worse — rounds 5/7). T5 setprio on
// the dbuf MFMA cluster measured null (round 8) — omitted. 256^2 tile
// kernel in-module measured net-negative via rule-#19 co-compilation
// regalloc perturbation (round 10: step-11 VGPR 76->88) — omitted.
// Split-K via blockIdx.z; partials at outv + z*4096*N; bias only on z==0.
//
// Block mapping: XCD chunking (contiguous t-range per XCD) composed with an
// 8-wide COLUMN-STRIPE supertile: consecutive t walk 8 bx-columns down gy
// rows. Per-XCD working set for step 10 (32x32 grid): 16 A + 8 B panels
// = 6 MB (vs 9 MB row-major, L2 = 4 MB/XCD) -> less B-panel thrash.
// gx=8 call-sites map to the identical footprint as row-major (no change).
// Bijective for all call sites (gx % 8 == 0).
//
// LDS stays LINEAR (global_load_lds); global source column group pre-swizzled
// by (l&7)^(l>>3); fragment reads XOR their column group with row&7
// (row&7 == lane&7 for all fragment rows).
template<int TM, bool HAS_RES, bool OUT_BF>
__global__ __launch_bounds__(TM == 128 ? 256 : 128)
void mgemm(const unsigned short* __restrict__ A, const unsigned short* __restrict__ Wt,
           const float* __restrict__ bias, const float* __restrict__ res,
           void* __restrict__ outv, int N, int K, int ldo, int vsplit,
           unsigned short* __restrict__ vtbuf, int kchunk)
{
  constexpr int NT = (TM == 128 ? 256 : 128);
  constexpr int NW = NT / 64;
  constexpr bool DBUF = (TM == 64);
  constexpr int AB_BYTES = (TM + 128) * 64 * 2 * (DBUF ? 2 : 1);
  constexpr int CS_BYTES = OUT_BF ? (TM * 136 * 2) : (64 * 132 * 4);
  constexpr int SMEM_BYTES = (AB_BYTES > CS_BYTES) ? AB_BYTES : CS_BYTES;
  __shared__ __align__(16) char smem[SMEM_BYTES];
  __bf16* As0 = (__bf16*)smem;           // [TM][64]
  __bf16* Bs0 = As0 + TM * 64;           // [128][64]
  __bf16* As1 = DBUF ? (Bs0 + 128 * 64) : As0;
  __bf16* Bs1 = DBUF ? (As1 + TM * 64) : Bs0;

  const int tid  = threadIdx.x;
  const int wave = tid >> 6, lane = tid & 63;
  const int wm = (TM == 128) ? (wave >> 1) : 0;
  const int wn = (TM == 128) ? (wave & 1) : wave;

  // XCD chunking + 8-wide column-stripe supertile (bijective: gx%8==0)
  int bx = blockIdx.x, by = blockIdx.y;
  {
    const int gx = gridDim.x, gy = gridDim.y;
    const int nwg = gx * gy;
    if ((nwg & 7) == 0 && (gx & 7) == 0) {
      const int id = by * gx + bx;
      const int t  = (id & 7) * (nwg >> 3) + (id >> 3);   // XCD chunk
      const int bxg = t & 7;
      const int r   = t >> 3;
      by = r % gy;
      bx = (r / gy) * 8 + bxg;
    }
  }
  const int bm = by * TM, bn = bx * 128;

  floatx4 acc[4][4];
  #pragma unroll
  for (int i = 0; i < 4; i++)
    #pragma unroll
    for (int j = 0; j < 4; j++) acc[i][j] = (floatx4)0.f;

  const int srow = (lane >> 3);
  const int scol = ((lane & 7) ^ srow) * 8;   // XOR-swizzled global source group

  auto stage = [&](int k0, __bf16* Asd, __bf16* Bsd) {
    #pragma unroll
    for (int j = 0; j < TM / (NW * 8); j++) {
      const int rbase = wave * (TM / NW) + j * 8;
      gload16(A + (size_t)(bm + rbase + srow) * K + k0 + scol, Asd + rbase * 64);
    }
    #pragma unroll
    for (int j = 0; j < 128 / (NW * 8); j++) {
      const int rbase = wave * (128 / NW) + j * 8;
      gload16(Wt + (size_t)(bn + rbase + srow) * K + k0 + scol, Bsd + rbase * 64);
    }
  };
  auto compute = [&](const __bf16* Asd, const __bf16* Bsd) {
    #pragma unroll
    for (int ks = 0; ks < 2; ks++) {
      // swizzled column group: logical kk = ks*32 + (lane>>4)*8, row&7 == lane&7
      const int kg = ((ks * 4 + (lane >> 4)) ^ (lane & 7)) * 8;
      const __bf16* Ab = Asd + (wm * 64 + (lane & 15)) * 64 + kg;
      const __bf16* Bb = Bsd + (wn * 64 + (lane & 15)) * 64 + kg;
      bf16x8 af[4], bf[4];
      #pragma unroll
      for (int mi = 0; mi < 4; mi++) af[mi] = *(const bf16x8*)(Ab + mi * 16 * 64);
      #pragma unroll
      for (int nj = 0; nj < 4; nj++) bf[nj] = *(const bf16x8*)(Bb + nj * 16 * 64);
      #pragma unroll
      for (int mi = 0; mi < 4; mi++)
        #pragma unroll
        for (int nj = 0; nj < 4; nj++)
          acc[mi][nj] = __builtin_amdgcn_mfma_f32_16x16x32_bf16(af[mi], bf[nj], acc[mi][nj], 0, 0, 0);
    }
  };

  const int kb = blockIdx.z * kchunk;
  if constexpr (DBUF) {
    const int nb = kchunk / 64;
    stage(kb, As0, Bs0);
    for (int i = 0; i < nb; i++) {
      const __bf16* Ac = (i & 1) ? As1 : As0;
      const __bf16* Bc = (i & 1) ? Bs1 : Bs0;
      if (i + 1 < nb) {
        asm volatile("s_barrier" ::: "memory");
        stage(kb + (i + 1) * 64, (i & 1) ? As0 : As1, (i & 1) ? Bs0 : Bs1);
        asm volatile("s_waitcnt vmcnt(12)" ::: "memory");
        asm volatile("s_barrier" ::: "memory");
      } else {
        asm volatile("s_waitcnt vmcnt(0)" ::: "memory");
        asm volatile("s_barrier" ::: "memory");
      }
      compute(Ac, Bc);
    }
    __syncthreads();
  } else {
    for (int k0 = kb; k0 < kb + kchunk; k0 += 64) {
      stage(k0, As0, Bs0);
      __syncthreads();
      compute(As0, Bs0);
      __syncthreads();
    }
  }

  const int lq = lane & 15, lg = lane >> 4;
  #pragma unroll
  for (int nj = 0; nj < 4; nj++) {
    const float bvn = (blockIdx.z == 0) ? bias[bn + wn * 64 + nj * 16 + lq] : 0.f;
    #pragma unroll
    for (int mi = 0; mi < 4; mi++)
      #pragma unroll
      for (int r = 0; r < 4; r++) acc[mi][nj][r] += bvn;
  }

  if constexpr (OUT_BF) {
    const bool vtile = (vtbuf != nullptr) && (bn >= vsplit);
    const int cst = vtile ? 132 : 136;
    __bf16* Cs = (__bf16*)smem;
    #pragma unroll
    for (int mi = 0; mi < 4; mi++)
      #pragma unroll
      for (int nj = 0; nj < 4; nj++)
        #pragma unroll
        for (int r = 0; r < 4; r++)
          Cs[(wm * 64 + mi * 16 + lg * 4 + r) * cst + wn * 64 + nj * 16 + lq] =
              (__bf16)acc[mi][nj][r];
    __syncthreads();
    const unsigned short* Cp = (const unsigned short*)Cs;
    if (!vtile) {
      #pragma unroll
      for (int it = 0; it < TM * 16 / NT; it++) {
        const int idx = tid + it * NT;
        const int row = idx >> 4, c8 = (idx & 15) * 8;
        uint4 v = *(const uint4*)(Cp + row * cst + c8);
        *(uint4*)((unsigned short*)outv + (size_t)(bm + row) * ldo + bn + c8) = v;
      }
    } else {
      const int bb = bm >> 10, tb = bm & 1023;
      #pragma unroll
      for (int it = 0; it < 128 * (TM / 8) / NT; it++) {
        const int idx = tid + it * NT;
        const int c_lo = idx & 15;
        const int tg = (idx >> 4) & (TM / 8 - 1);
        const int c_hi = idx >> (4 + (TM == 128 ? 4 : 3));
        const int col = c_hi * 16 + c_lo;
        unsigned short tmp[8];
        #pragma unroll
        for (int i = 0; i < 8; i++) tmp[i] = Cp[(tg * 8 + i) * cst + col];
        uint4 ov;
        unsigned short* po = (unsigned short*)&ov;
        #pragma unroll
        for (int i = 0; i < 8; i++) po[i] = tmp[i];
        const int dd = bn + col - vsplit;
        *(uint4*)(vtbuf + (size_t)(bb * 1024 + dd) * T_ + tb + tg * 8) = ov;
      }
    }
  } else {
    float* outp = (float*)outv + (size_t)blockIdx.z * ((size_t)4096 * N);
    float* Csf = (float*)smem;           // [64][132]
    constexpr int PASSES = TM / 64;
    #pragma unroll
    for (int p = 0; p < PASSES; p++) {
      if (wm == p) {
        #pragma unroll
        for (int mi = 0; mi < 4; mi++)
          #pragma unroll
          for (int nj = 0; nj < 4; nj++)
            #pragma unroll
            for (int r = 0; r < 4; r++)
              Csf[(mi * 16 + lg * 4 + r) * 132 + wn * 64 + nj * 16 + lq] = acc[mi][nj][r];
      }
      __syncthreads();
      #pragma unroll
      for (int it = 0; it < 2048 / NT; it++) {
        const int idx = tid + it * NT;
        const int row = idx >> 5, c4 = (idx & 31) * 4;
        float4 v = *(const float4*)(Csf + row * 132 + c4);
        const size_t m = (size_t)bm + p * 64 + row;
        if constexpr (HAS_RES) {
          float4 f = *(const float4*)(res + m * N + bn + c4);
          v.x += f.x; v.y += f.y; v.z += f.z; v.w += f.w;
        }
        *(float4*)(outp + m * N + bn + c4) = v;
      }
      if (p + 1 < PASSES) __syncthreads();
    }
  }
}

// ---------- bf16 MFMA flash attention (v4: max-free softmax, MFMA row-sum) ----------
// grid (T/64, B*H), 256 thr = 4 waves; wave = 16-row Q strip.
// Max-free softmax (|S*SC| ~ O(3) << 127 exp2 overflow); row-sum via
// mfma(P, ones). __launch_bounds__(256,8) pins VGPR<=64 (m69 cliff).
// 25.6 KB LDS -> 6 blocks/CU = 24 waves/CU: this occupancy is the latency
// cover; rounds 3/9 proved any variant that cuts it loses.
__global__ __launch_bounds__(256, 8)
void mattn(const unsigned short* __restrict__ Qg, int ldq,
           const unsigned short* __restrict__ Kg, int ldk,
           const unsigned short* __restrict__ Vtg,
           unsigned short* __restrict__ Og)
{
  __shared__ __align__(16) __bf16 Ks[64 * 64];
  __shared__ __align__(16) __bf16 Vt[64 * 64];
  __shared__ __align__(16) __bf16 Ps[4 * 16 * 72];
  const int tid = threadIdx.x, w = tid >> 6, l = tid & 63;
  const int bh = blockIdx.y, b = bh >> 4, h = bh & 15;
  const int q0 = blockIdx.x * 64;
  const int lq = l & 15, qd = l >> 4;
  const float SC = 0.18033688f;   // 0.125 * log2(e)

  const unsigned short* Qb = Qg + (size_t)(b * T_ + q0) * ldq + h * 64;
  bf16x8 aq[2];
  aq[0] = *(const bf16x8*)(Qb + (size_t)(w * 16 + lq) * ldq + qd * 8);
  aq[1] = *(const bf16x8*)(Qb + (size_t)(w * 16 + lq) * ldq + qd * 8 + 32);

  bf16x8 ones;
  #pragma unroll
  for (int i = 0; i < 8; i++) ones[i] = (__bf16)1.0f;

  floatx4 accO[4];
  #pragma unroll
  for (int nj = 0; nj < 4; nj++) accO[nj] = (floatx4)0.f;
  floatx4 accL = (floatx4)0.f;
  __bf16* pw = Ps + w * 16 * 72;

  const int sg = ((l & 7) ^ (l >> 3)) * 8;
  const int srow = l >> 3;

  for (int kt = 0; kt < T_; kt += 64) {
    const unsigned short* Kb = Kg + (size_t)(b * T_ + kt) * ldk + h * 64;
    const unsigned short* Vb = Vtg + (size_t)bh * 64 * T_ + kt;
    #pragma unroll
    for (int j = 0; j < 2; j++) {
      const int r0 = w * 16 + j * 8;
      gload16(Kb + (size_t)(r0 + srow) * ldk + sg, Ks + r0 * 64);
      gload16(Vb + (size_t)(r0 + srow) * T_  + sg, Vt + r0 * 64);
    }
    __syncthreads();

    floatx4 s[4];
    #pragma unroll
    for (int nj = 0; nj < 4; nj++) s[nj] = (floatx4)0.f;
    __builtin_amdgcn_s_setprio(1);
    #pragma unroll
    for (int ks = 0; ks < 2; ks++) {
      const int kg = ((qd + ks * 4) ^ (lq & 7)) * 8;  // swizzled col group
      #pragma unroll
      for (int nj = 0; nj < 4; nj++) {
        bf16x8 bk = *(const bf16x8*)(Ks + (nj * 16 + lq) * 64 + kg);
        s[nj] = __builtin_amdgcn_mfma_f32_16x16x32_bf16(aq[ks], bk, s[nj], 0, 0, 0);
      }
    }
    __builtin_amdgcn_s_setprio(0);

    #pragma unroll
    for (int nj = 0; nj < 4; nj++)
      #pragma unroll
      for (int r = 0; r < 4; r++)
        s[nj][r] = exp2_raw(s[nj][r] * SC);

    #pragma unroll
    for (int r = 0; r < 4; r++)
      #pragma unroll
      for (int nj = 0; nj < 4; nj++)
        pw[(qd * 4 + r) * 72 + nj * 16 + lq] = (__bf16)s[nj][r];

    __builtin_amdgcn_s_setprio(1);
    #pragma unroll
    for (int ks = 0; ks < 2; ks++) {
      const int kg = ((qd + ks * 4) ^ (lq & 7)) * 8;  // swizzled col group
      bf16x8 ap = *(const bf16x8*)(pw + lq * 72 + qd * 8 + ks * 32);
      #pragma unroll
      for (int nj = 0; nj < 4; nj++) {
        bf16x8 bv = *(const bf16x8*)(Vt + (nj * 16 + lq) * 64 + kg);
        accO[nj] = __builtin_amdgcn_mfma_f32_16x16x32_bf16(ap, bv, accO[nj], 0, 0, 0);
      }
      accL = __builtin_amdgcn_mfma_f32_16x16x32_bf16(ap, ones, accL, 0, 0, 0);
    }
    __builtin_amdgcn_s_setprio(0);
    __syncthreads();
  }

  unsigned short* Ob = Og + (size_t)(b * T_ + q0) * C_ + h * 64;
  #pragma unroll
  for (int r = 0; r < 4; r++) {
    const float inv = 1.f / accL[r];
    const int row = w * 16 + qd * 4 + r;
    #pragma unroll
    for (int nj = 0; nj < 4; nj++)
      Ob[(size_t)row * C_ + nj * 16 + lq] = f2bf(accO[nj][r] * inv);
  }
}

// ---------- LayerNorm over C=1024, fp32 out (+ optional bf16 copy) ----------
template<bool DUAL>
__global__ __launch_bounds__(256)
void ln_k(const float* __restrict__ in, const float* __restrict__ w,
          const float* __restrict__ b, float* __restrict__ out,
          unsigned short* __restrict__ out_bf)
{
  __shared__ float red[8];
  const int row = blockIdx.x, tid = threadIdx.x;
  float4 v = *(const float4*)(in + (size_t)row * C_ + tid * 4);
  float s = v.x + v.y + v.z + v.w;
  #pragma unroll
  for (int off = 32; off > 0; off >>= 1) s += __shfl_down(s, off, 64);
  if ((tid & 63) == 0) red[tid >> 6] = s;
  __syncthreads();
  const float mu = (red[0] + red[1] + red[2] + red[3]) * (1.f / C_);
  const float dx = v.x - mu, dy = v.y - mu, dz = v.z - mu, dw = v.w - mu;
  float ss = dx*dx + dy*dy + dz*dz + dw*dw;
  #pragma unroll
  for (int off = 32; off > 0; off >>= 1) ss += __shfl_down(ss, off, 64);
  if ((tid & 63) == 0) red[4 + (tid >> 6)] = ss;
  __syncthreads();
  const float rinv = rsqrtf((red[4] + red[5] + red[6] + red[7]) * (1.f / C_) + 1e-5f);
  float4 wv = *(const float4*)(w + tid * 4);
  float4 bv = *(const float4*)(b + tid * 4);
  float4 o;
  o.x = dx * rinv * wv.x + bv.x;
  o.y = dy * rinv * wv.y + bv.y;
  o.z = dz * rinv * wv.z + bv.z;
  o.w = dw * rinv * wv.w + bv.w;
  *(float4*)(out + (size_t)row * C_ + tid * 4) = o;
  if constexpr (DUAL) {
    ushort4 o4; o4.x = f2bf(o.x); o4.y = f2bf(o.y); o4.z = f2bf(o.z); o4.w = f2bf(o.w);
    *(ushort4*)(out_bf + (size_t)row * C_ + tid * 4) = o4;
  }
}

// ---------- fused: sum NS split-K partials + residual, then LayerNorm ----------
template<int NS>
__global__ __launch_bounds__(256)
void ln_red(const float* __restrict__ p, const float* __restrict__ resid,
            const float* __restrict__ w, const float* __restrict__ b,
            float* __restrict__ out)
{
  __shared__ float red[8];
  const int row = blockIdx.x, tid = threadIdx.x;
  const size_t off = (size_t)row * C_ + tid * 4;
  const size_t st = (size_t)M_ * C_;
  float4 v = *(const float4*)(p + off);
  #pragma unroll
  for (int i = 1; i < NS; i++) {
    float4 vi = *(const float4*)(p + i * st + off);
    v.x += vi.x; v.y += vi.y; v.z += vi.z; v.w += vi.w;
  }
  float4 rr = *(const float4*)(resid + off);
  v.x += rr.x; v.y += rr.y; v.z += rr.z; v.w += rr.w;
  float s = v.x + v.y + v.z + v.w;
  #pragma unroll
  for (int o = 32; o > 0; o >>= 1) s += __shfl_down(s, o, 64);
  if ((tid & 63) == 0) red[tid >> 6] = s;
  __syncthreads();
  const float mu = (red[0] + red[1] + red[2] + red[3]) * (1.f / C_);
  const float dx = v.x - mu, dy = v.y - mu, dz = v.z - mu, dw = v.w - mu;
  float ss = dx*dx + dy*dy + dz*dz + dw*dw;
  #pragma unroll
  for (int o = 32; o > 0; o >>= 1) ss += __shfl_down(ss, o, 64);
  if ((tid & 63) == 0) red[4 + (tid >> 6)] = ss;
  __syncthreads();
  const float rinv = rsqrtf((red[4] + red[5] + red[6] + red[7]) * (1.f / C_) + 1e-5f);
  float4 wv = *(const float4*)(w + tid * 4);
  float4 bv = *(const float4*)(b + tid * 4);
  float4 o;
  o.x = dx * rinv * wv.x + bv.x;
  o.y = dy * rinv * wv.y + bv.y;
  o.z = dz * rinv * wv.z + bv.z;
  o.w = dw * rinv * wv.w + bv.w;
  *(float4*)(out + off) = o;
}

extern "C" void kernel_launch(void* const* d_in, const int* in_sizes, int n_in,
                              void* d_out, int out_size, void* d_ws, size_t ws_size,
                              hipStream_t stream)
{
  const float* x       = (const float*)d_in[0];
  const float* y       = (const float*)d_in[1];
  const float* W_attn  = (const float*)d_in[2];
  const float* b_attn  = (const float*)d_in[3];
  const float* W_proj  = (const float*)d_in[4];
  const float* b_proj  = (const float*)d_in[5];
  const float* ln_w    = (const float*)d_in[6];
  const float* ln_b    = (const float*)d_in[7];
  const float* W_en    = (const float*)d_in[8];
  const float* b_en    = (const float*)d_in[9];
  const float* W_q     = (const float*)d_in[10];
  const float* b_q     = (const float*)d_in[11];
  const float* W_cproj = (const float*)d_in[12];
  const float* b_cproj = (const float*)d_in[13];
  const float* ln1_w   = (const float*)d_in[14];
  const float* ln1_b   = (const float*)d_in[15];
  const float* ln2_w   = (const float*)d_in[16];
  const float* ln2_b   = (const float*)d_in[17];
  const float* W_d1    = (const float*)d_in[18];
  const float* b_d1    = (const float*)d_in[19];
  const float* W_d2    = (const float*)d_in[20];
  const float* b_d2    = (const float*)d_in[21];

  char* wsb = (char*)d_ws;
  const size_t MB = 1024 * 1024;
  unsigned short* wt_attn  = (unsigned short*)(wsb + 0 * MB);
  unsigned short* wt_proj  = (unsigned short*)(wsb + 6 * MB);
  unsigned short* wt_en    = (unsigned short*)(wsb + 8 * MB);
  unsigned short* wt_q     = (unsigned short*)(wsb + 12 * MB);
  unsigned short* wt_cproj = (unsigned short*)(wsb + 14 * MB);
  unsigned short* wt_d1    = (unsigned short*)(wsb + 16 * MB);
  unsigned short* wt_d2    = (unsigned short*)(wsb + 24 * MB);
  unsigned short* y_bf     = (unsigned short*)(wsb + 32 * MB);
  unsigned short* yb_bf    = y_bf;
  unsigned short* x_bf     = (unsigned short*)(wsb + 40 * MB);
  unsigned short* xin_bf   = x_bf;
  unsigned short* qkvb     = (unsigned short*)(wsb + 48 * MB);   // [M][2048] Q|K
  unsigned short* vt1      = (unsigned short*)(wsb + 64 * MB);   // [B*16][64][T]
  unsigned short* kvK      = (unsigned short*)(wsb + 72 * MB);   // [M][1024]
  unsigned short* vt2      = (unsigned short*)(wsb + 80 * MB);
  unsigned short* q2b      = (unsigned short*)(wsb + 88 * MB);
  unsigned short* o1_bf    = (unsigned short*)(wsb + 96 * MB);
  unsigned short* o2_bf    = o1_bf;
  float*          yb       = (float*)(wsb + 104 * MB);
  float*          xin      = (float*)(wsb + 120 * MB);
  unsigned short* h_bf     = (unsigned short*)(wsb + 136 * MB);
  float*          part     = (float*)(wsb + 48 * MB);  // step-11 partials, 2x16MB (48..80MB all dead by step 11)
  float*          z        = (float*)d_out;

  const dim3 b256(256), b128(128);

  // --- prep ---
  conv_f2b<<<dim3(M_*C_/1024), b256, 0, stream>>>(y, y_bf);
  conv_f2b<<<dim3(M_*C_/1024), b256, 0, stream>>>(x, x_bf);
  transpose_conv<<<dim3(96, 32),  b256, 0, stream>>>(W_attn,  wt_attn,  C_, 3*C_);
  transpose_conv<<<dim3(32, 32),  b256, 0, stream>>>(W_proj,  wt_proj,  C_, C_);
  transpose_conv<<<dim3(64, 32),  b256, 0, stream>>>(W_en,    wt_en,    C_, 2*C_);
  transpose_conv<<<dim3(32, 32),  b256, 0, stream>>>(W_q,     wt_q,     C_, C_);
  transpose_conv<<<dim3(32, 32),  b256, 0, stream>>>(W_cproj, wt_cproj, C_, C_);
  transpose_conv<<<dim3(128, 32), b256, 0, stream>>>(W_d1,    wt_d1,    C_, DFF_);
  transpose_conv<<<dim3(32, 128), b256, 0, stream>>>(W_d2,    wt_d2,    DFF_, C_);

  // 1. qkv = y @ W_attn + b_attn -> Q|K bf16 [M][2048], V -> vt1 (transposed)
  mgemm<128, false, true><<<dim3(24, 32), b256, 0, stream>>>(y_bf, wt_attn, b_attn, nullptr, qkvb, 3*C_, C_, 2048, 2048, vt1, C_);
  // 2. self-attention -> o1 (bf16)
  mattn<<<dim3(T_/64, B_*H_), b256, 0, stream>>>(qkvb, 2048, qkvb + 1024, 2048, vt1, o1_bf);
  // 3. y1 = o1 @ W_proj + b_proj + y  (fp32)  [TM=64 dbuf: measured-best for this shape]
  mgemm<64, true, false><<<dim3(8, 64), b128, 0, stream>>>(o1_bf, wt_proj, b_proj, y, yb, C_, C_, C_, C_, nullptr, C_);
  // 4. y2 = LN(y1) in-place, dual out
  ln_k<true><<<dim3(M_), b256, 0, stream>>>(yb, ln_w, ln_b, yb, yb_bf);
  // 5. kv = x @ W_en + b_en -> K bf16 [M][1024], V -> vt2 (transposed)
  mgemm<128, false, true><<<dim3(16, 32), b256, 0, stream>>>(x_bf, wt_en, b_en, nullptr, kvK, 2*C_, C_, 1024, 1024, vt2, C_);
  // 6. q2 = y2 @ W_q + b_q (bf16)  [TM=64 dbuf]
  mgemm<64, false, true><<<dim3(8, 64), b128, 0, stream>>>(yb_bf, wt_q, b_q, nullptr, q2b, C_, C_, 1024, C_, nullptr, C_);
  // 7. cross-attention -> o2 (bf16)
  mattn<<<dim3(T_/64, B_*H_), b256, 0, stream>>>(q2b, 1024, kvK, 1024, vt2, o2_bf);
  // 8. y3 = o2 @ W_cproj + b_cproj + y2  (fp32 -> xin)  [TM=64 dbuf]
  mgemm<64, true, false><<<dim3(8, 64), b128, 0, stream>>>(o2_bf, wt_cproj, b_cproj, yb, xin, C_, C_, C_, C_, nullptr, C_);
  // 9. x_in = LN(y3) in-place, dual out
  ln_k<true><<<dim3(M_), b256, 0, stream>>>(xin, ln1_w, ln1_b, xin, xin_bf);
  // 10. h = x_in @ W_d1 + b_d1  (bf16)
  mgemm<128, false, true><<<dim3(32, 32), b256, 0, stream>>>(xin_bf, wt_d1, b_d1, nullptr, h_bf, DFF_, C_, DFF_, DFF_, nullptr, C_);
  // 11. z-partials = h @ W_d2 (+b_d2 on z==0), split-K=2 over DFF (TM=128)
  mgemm<128, false, false><<<dim3(8, 32, 2), b256, 0, stream>>>(h_bf, wt_d2, b_d2, nullptr, part, C_, DFF_, C_, C_, nullptr, 2048);
  // 12. out = LN(p0+p1 + xin)  -> d_out
  ln_red<2><<<dim3(M_), b256, 0, stream>>>(part, xin, ln2_w, ln2_b, z);
}

// Round 14
// 471.368 us; speedup vs baseline: 1.0483x; 1.0483x over previous
//
#include <hip/hip_runtime.h>

#define B_ 4
#define T_ 1024
#define C_ 1024
#define H_ 16
#define HD_ 64
#define DFF_ 4096
#define M_ (B_*T_)

typedef __bf16 bf16x8 __attribute__((ext_vector_type(8)));
typedef float floatx4 __attribute__((ext_vector_type(4)));

__device__ __forceinline__ unsigned short f2bf(float f) {
  unsigned int x = __float_as_uint(f);
  x += 0x7fffu + ((x >> 16) & 1u);   // round-to-nearest-even
  return (unsigned short)(x >> 16);
}

__device__ __forceinline__ float exp2_raw(float x) {
  float r; asm("v_exp_f32 %0, %1" : "=v"(r) : "v"(x)); return r;
}

__device__ __forceinline__ void gload16(const void* g, void* l) {
  __builtin_amdgcn_global_load_lds(
      (const __attribute__((address_space(1))) unsigned int*)g,
      (__attribute__((address_space(3))) unsigned int*)l, 16, 0, 0);
}

// ---------- fp32 -> bf16 elementwise (4 elems/thread) ----------
__global__ __launch_bounds__(256)
void conv_f2b(const float* __restrict__ in, unsigned short* __restrict__ out) {
  const size_t i = ((size_t)blockIdx.x * 256 + threadIdx.x) * 4;
  float4 v = *(const float4*)(in + i);
  ushort4 o; o.x = f2bf(v.x); o.y = f2bf(v.y); o.z = f2bf(v.z); o.w = f2bf(v.w);
  *(ushort4*)(out + i) = o;
}

// ---------- W[K][N] fp32 -> Wt[N][K] bf16 (32x32 LDS tile) ----------
__global__ __launch_bounds__(256)
void transpose_conv(const float* __restrict__ W, unsigned short* __restrict__ Wt,
                    int K, int N) {
  __shared__ float Ts[32][33];
  const int t = threadIdx.x;
  const int bn = blockIdx.x * 32, bk = blockIdx.y * 32;
  const int r = t >> 5, c = t & 31;
  #pragma unroll
  for (int i = 0; i < 4; i++)
    Ts[r + i * 8][c] = W[(size_t)(bk + r + i * 8) * N + bn + c];
  __syncthreads();
  #pragma unroll
  for (int i = 0; i < 4; i++)
    Wt[(size_t)(bn + r + i * 8) * K + bk + c] = f2bf(Ts[c][r + i * 8]);
}

// ---------- bf16 MFMA GEMM: out = A @ Wt^T + bias (+res) ----------
// A: [M][K] bf16.  Wt: [N][K] bf16.  Tile TM x 128, BK=64.
// TM=128: 256 thr / 4 waves, single-buffered (m97 structure).
// TM=64 : 128 thr / 2 waves, double-buffered LDS (s_barrier + vmcnt(12)):
// measured-best for skinny M=4096/N=1024/K=1024.
//
// Block mapping:
//  - TM=128 (all call sites have gridDim.y==32): XCD chunk + 8-wide
//    column-stripe supertile, SHIFT/MASK ONLY (round-13 lesson: the
//    runtime %/ division inflated VGPR 76->88 across ALL instantiations
//    and cost ~18us in the TM=64 steps; per-dispatch the stripe was
//    measured -4..-7us on steps 10/11 with FETCH 75->49 MB).
//  - TM=64: exact round-12 row-major XCD chunk (restores the 482.9-build
//    codegen for the occupancy-sensitive dbuf kernels).
// T5 setprio on dbuf: null (round 8). 256^2 in-module: rule-#19 negative
// (round 10). Split-K via blockIdx.z; bias only on z==0.
//
// LDS stays LINEAR (global_load_lds); global source column group pre-swizzled
// by (l&7)^(l>>3); fragment reads XOR their column group with row&7
// (row&7 == lane&7 for all fragment rows).
template<int TM, bool HAS_RES, bool OUT_BF>
__global__ __launch_bounds__(TM == 128 ? 256 : 128)
void mgemm(const unsigned short* __restrict__ A, const unsigned short* __restrict__ Wt,
           const float* __restrict__ bias, const float* __restrict__ res,
           void* __restrict__ outv, int N, int K, int ldo, int vsplit,
           unsigned short* __restrict__ vtbuf, int kchunk)
{
  constexpr int NT = (TM == 128 ? 256 : 128);
  constexpr int NW = NT / 64;
  constexpr bool DBUF = (TM == 64);
  constexpr int AB_BYTES = (TM + 128) * 64 * 2 * (DBUF ? 2 : 1);
  constexpr int CS_BYTES = OUT_BF ? (TM * 136 * 2) : (64 * 132 * 4);
  constexpr int SMEM_BYTES = (AB_BYTES > CS_BYTES) ? AB_BYTES : CS_BYTES;
  __shared__ __align__(16) char smem[SMEM_BYTES];
  __bf16* As0 = (__bf16*)smem;           // [TM][64]
  __bf16* Bs0 = As0 + TM * 64;           // [128][64]
  __bf16* As1 = DBUF ? (Bs0 + 128 * 64) : As0;
  __bf16* Bs1 = DBUF ? (As1 + TM * 64) : Bs0;

  const int tid  = threadIdx.x;
  const int wave = tid >> 6, lane = tid & 63;
  const int wm = (TM == 128) ? (wave >> 1) : 0;
  const int wn = (TM == 128) ? (wave & 1) : wave;

  int bx = blockIdx.x, by = blockIdx.y;
  {
    const int gx = gridDim.x;
    const int nwg = gx * gridDim.y;
    if ((nwg & 7) == 0) {
      const int id = by * gx + bx;
      const int t  = (id & 7) * (nwg >> 3) + (id >> 3);   // XCD chunk
      if constexpr (TM == 128) {
        // column-stripe supertile; all TM=128 call sites have gridDim.y==32
        const int bxg = t & 7;
        const int r   = t >> 3;
        by = r & 31;
        bx = (r >> 5) * 8 + bxg;
      } else {
        bx = t % gx; by = t / gx;
      }
    }
  }
  const int bm = by * TM, bn = bx * 128;

  floatx4 acc[4][4];
  #pragma unroll
  for (int i = 0; i < 4; i++)
    #pragma unroll
    for (int j = 0; j < 4; j++) acc[i][j] = (floatx4)0.f;

  const int srow = (lane >> 3);
  const int scol = ((lane & 7) ^ srow) * 8;   // XOR-swizzled global source group

  auto stage = [&](int k0, __bf16* Asd, __bf16* Bsd) {
    #pragma unroll
    for (int j = 0; j < TM / (NW * 8); j++) {
      const int rbase = wave * (TM / NW) + j * 8;
      gload16(A + (size_t)(bm + rbase + srow) * K + k0 + scol, Asd + rbase * 64);
    }
    #pragma unroll
    for (int j = 0; j < 128 / (NW * 8); j++) {
      const int rbase = wave * (128 / NW) + j * 8;
      gload16(Wt + (size_t)(bn + rbase + srow) * K + k0 + scol, Bsd + rbase * 64);
    }
  };
  auto compute = [&](const __bf16* Asd, const __bf16* Bsd) {
    #pragma unroll
    for (int ks = 0; ks < 2; ks++) {
      // swizzled column group: logical kk = ks*32 + (lane>>4)*8, row&7 == lane&7
      const int kg = ((ks * 4 + (lane >> 4)) ^ (lane & 7)) * 8;
      const __bf16* Ab = Asd + (wm * 64 + (lane & 15)) * 64 + kg;
      const __bf16* Bb = Bsd + (wn * 64 + (lane & 15)) * 64 + kg;
      bf16x8 af[4], bf[4];
      #pragma unroll
      for (int mi = 0; mi < 4; mi++) af[mi] = *(const bf16x8*)(Ab + mi * 16 * 64);
      #pragma unroll
      for (int nj = 0; nj < 4; nj++) bf[nj] = *(const bf16x8*)(Bb + nj * 16 * 64);
      #pragma unroll
      for (int mi = 0; mi < 4; mi++)
        #pragma unroll
        for (int nj = 0; nj < 4; nj++)
          acc[mi][nj] = __builtin_amdgcn_mfma_f32_16x16x32_bf16(af[mi], bf[nj], acc[mi][nj], 0, 0, 0);
    }
  };

  const int kb = blockIdx.z * kchunk;
  if constexpr (DBUF) {
    const int nb = kchunk / 64;
    stage(kb, As0, Bs0);
    for (int i = 0; i < nb; i++) {
      const __bf16* Ac = (i & 1) ? As1 : As0;
      const __bf16* Bc = (i & 1) ? Bs1 : Bs0;
      if (i + 1 < nb) {
        asm volatile("s_barrier" ::: "memory");
        stage(kb + (i + 1) * 64, (i & 1) ? As0 : As1, (i & 1) ? Bs0 : Bs1);
        asm volatile("s_waitcnt vmcnt(12)" ::: "memory");
        asm volatile("s_barrier" ::: "memory");
      } else {
        asm volatile("s_waitcnt vmcnt(0)" ::: "memory");
        asm volatile("s_barrier" ::: "memory");
      }
      compute(Ac, Bc);
    }
    __syncthreads();
  } else {
    for (int k0 = kb; k0 < kb + kchunk; k0 += 64) {
      stage(k0, As0, Bs0);
      __syncthreads();
      compute(As0, Bs0);
      __syncthreads();
    }
  }

  const int lq = lane & 15, lg = lane >> 4;
  #pragma unroll
  for (int nj = 0; nj < 4; nj++) {
    const float bvn = (blockIdx.z == 0) ? bias[bn + wn * 64 + nj * 16 + lq] : 0.f;
    #pragma unroll
    for (int mi = 0; mi < 4; mi++)
      #pragma unroll
      for (int r = 0; r < 4; r++) acc[mi][nj][r] += bvn;
  }

  if constexpr (OUT_BF) {
    const bool vtile = (vtbuf != nullptr) && (bn >= vsplit);
    const int cst = vtile ? 132 : 136;
    __bf16* Cs = (__bf16*)smem;
    #pragma unroll
    for (int mi = 0; mi < 4; mi++)
      #pragma unroll
      for (int nj = 0; nj < 4; nj++)
        #pragma unroll
        for (int r = 0; r < 4; r++)
          Cs[(wm * 64 + mi * 16 + lg * 4 + r) * cst + wn * 64 + nj * 16 + lq] =
              (__bf16)acc[mi][nj][r];
    __syncthreads();
    const unsigned short* Cp = (const unsigned short*)Cs;
    if (!vtile) {
      #pragma unroll
      for (int it = 0; it < TM * 16 / NT; it++) {
        const int idx = tid + it * NT;
        const int row = idx >> 4, c8 = (idx & 15) * 8;
        uint4 v = *(const uint4*)(Cp + row * cst + c8);
        *(uint4*)((unsigned short*)outv + (size_t)(bm + row) * ldo + bn + c8) = v;
      }
    } else {
      const int bb = bm >> 10, tb = bm & 1023;
      #pragma unroll
      for (int it = 0; it < 128 * (TM / 8) / NT; it++) {
        const int idx = tid + it * NT;
        const int c_lo = idx & 15;
        const int tg = (idx >> 4) & (TM / 8 - 1);
        const int c_hi = idx >> (4 + (TM == 128 ? 4 : 3));
        const int col = c_hi * 16 + c_lo;
        unsigned short tmp[8];
        #pragma unroll
        for (int i = 0; i < 8; i++) tmp[i] = Cp[(tg * 8 + i) * cst + col];
        uint4 ov;
        unsigned short* po = (unsigned short*)&ov;
        #pragma unroll
        for (int i = 0; i < 8; i++) po[i] = tmp[i];
        const int dd = bn + col - vsplit;
        *(uint4*)(vtbuf + (size_t)(bb * 1024 + dd) * T_ + tb + tg * 8) = ov;
      }
    }
  } else {
    float* outp = (float*)outv + (size_t)blockIdx.z * ((size_t)4096 * N);
    float* Csf = (float*)smem;           // [64][132]
    constexpr int PASSES = TM / 64;
    #pragma unroll
    for (int p = 0; p < PASSES; p++) {
      if (wm == p) {
        #pragma unroll
        for (int mi = 0; mi < 4; mi++)
          #pragma unroll
          for (int nj = 0; nj < 4; nj++)
            #pragma unroll
            for (int r = 0; r < 4; r++)
              Csf[(mi * 16 + lg * 4 + r) * 132 + wn * 64 + nj * 16 + lq] = acc[mi][nj][r];
      }
      __syncthreads();
      #pragma unroll
      for (int it = 0; it < 2048 / NT; it++) {
        const int idx = tid + it * NT;
        const int row = idx >> 5, c4 = (idx & 31) * 4;
        float4 v = *(const float4*)(Csf + row * 132 + c4);
        const size_t m = (size_t)bm + p * 64 + row;
        if constexpr (HAS_RES) {
          float4 f = *(const float4*)(res + m * N + bn + c4);
          v.x += f.x; v.y += f.y; v.z += f.z; v.w += f.w;
        }
        *(float4*)(outp + m * N + bn + c4) = v;
      }
      if (p + 1 < PASSES) __syncthreads();
    }
  }
}

// ---------- bf16 MFMA flash attention (v4: max-free softmax, MFMA row-sum) ----------
// grid (T/64, B*H), 256 thr = 4 waves; wave = 16-row Q strip.
// Max-free softmax (|S*SC| ~ O(3) << 127 exp2 overflow); row-sum via
// mfma(P, ones). __launch_bounds__(256,8) pins VGPR<=64 (m69 cliff).
// 25.6 KB LDS -> 6 blocks/CU = 24 waves/CU: this occupancy is the latency
// cover; rounds 3/9 proved any variant that cuts it loses.
__global__ __launch_bounds__(256, 8)
void mattn(const unsigned short* __restrict__ Qg, int ldq,
           const unsigned short* __restrict__ Kg, int ldk,
           const unsigned short* __restrict__ Vtg,
           unsigned short* __restrict__ Og)
{
  __shared__ __align__(16) __bf16 Ks[64 * 64];
  __shared__ __align__(16) __bf16 Vt[64 * 64];
  __shared__ __align__(16) __bf16 Ps[4 * 16 * 72];
  const int tid = threadIdx.x, w = tid >> 6, l = tid & 63;
  const int bh = blockIdx.y, b = bh >> 4, h = bh & 15;
  const int q0 = blockIdx.x * 64;
  const int lq = l & 15, qd = l >> 4;
  const float SC = 0.18033688f;   // 0.125 * log2(e)

  const unsigned short* Qb = Qg + (size_t)(b * T_ + q0) * ldq + h * 64;
  bf16x8 aq[2];
  aq[0] = *(const bf16x8*)(Qb + (size_t)(w * 16 + lq) * ldq + qd * 8);
  aq[1] = *(const bf16x8*)(Qb + (size_t)(w * 16 + lq) * ldq + qd * 8 + 32);

  bf16x8 ones;
  #pragma unroll
  for (int i = 0; i < 8; i++) ones[i] = (__bf16)1.0f;

  floatx4 accO[4];
  #pragma unroll
  for (int nj = 0; nj < 4; nj++) accO[nj] = (floatx4)0.f;
  floatx4 accL = (floatx4)0.f;
  __bf16* pw = Ps + w * 16 * 72;

  const int sg = ((l & 7) ^ (l >> 3)) * 8;
  const int srow = l >> 3;

  for (int kt = 0; kt < T_; kt += 64) {
    const unsigned short* Kb = Kg + (size_t)(b * T_ + kt) * ldk + h * 64;
    const unsigned short* Vb = Vtg + (size_t)bh * 64 * T_ + kt;
    #pragma unroll
    for (int j = 0; j < 2; j++) {
      const int r0 = w * 16 + j * 8;
      gload16(Kb + (size_t)(r0 + srow) * ldk + sg, Ks + r0 * 64);
      gload16(Vb + (size_t)(r0 + srow) * T_  + sg, Vt + r0 * 64);
    }
    __syncthreads();

    floatx4 s[4];
    #pragma unroll
    for (int nj = 0; nj < 4; nj++) s[nj] = (floatx4)0.f;
    __builtin_amdgcn_s_setprio(1);
    #pragma unroll
    for (int ks = 0; ks < 2; ks++) {
      const int kg = ((qd + ks * 4) ^ (lq & 7)) * 8;  // swizzled col group
      #pragma unroll
      for (int nj = 0; nj < 4; nj++) {
        bf16x8 bk = *(const bf16x8*)(Ks + (nj * 16 + lq) * 64 + kg);
        s[nj] = __builtin_amdgcn_mfma_f32_16x16x32_bf16(aq[ks], bk, s[nj], 0, 0, 0);
      }
    }
    __builtin_amdgcn_s_setprio(0);

    #pragma unroll
    for (int nj = 0; nj < 4; nj++)
      #pragma unroll
      for (int r = 0; r < 4; r++)
        s[nj][r] = exp2_raw(s[nj][r] * SC);

    #pragma unroll
    for (int r = 0; r < 4; r++)
      #pragma unroll
      for (int nj = 0; nj < 4; nj++)
        pw[(qd * 4 + r) * 72 + nj * 16 + lq] = (__bf16)s[nj][r];

    __builtin_amdgcn_s_setprio(1);
    #pragma unroll
    for (int ks = 0; ks < 2; ks++) {
      const int kg = ((qd + ks * 4) ^ (lq & 7)) * 8;  // swizzled col group
      bf16x8 ap = *(const bf16x8*)(pw + lq * 72 + qd * 8 + ks * 32);
      #pragma unroll
      for (int nj = 0; nj < 4; nj++) {
        bf16x8 bv = *(const bf16x8*)(Vt + (nj * 16 + lq) * 64 + kg);
        accO[nj] = __builtin_amdgcn_mfma_f32_16x16x32_bf16(ap, bv, accO[nj], 0, 0, 0);
      }
      accL = __builtin_amdgcn_mfma_f32_16x16x32_bf16(ap, ones, accL, 0, 0, 0);
    }
    __builtin_amdgcn_s_setprio(0);
    __syncthreads();
  }

  unsigned short* Ob = Og + (size_t)(b * T_ + q0) * C_ + h * 64;
  #pragma unroll
  for (int r = 0; r < 4; r++) {
    const float inv = 1.f / accL[r];
    const int row = w * 16 + qd * 4 + r;
    #pragma unroll
    for (int nj = 0; nj < 4; nj++)
      Ob[(size_t)row * C_ + nj * 16 + lq] = f2bf(accO[nj][r] * inv);
  }
}

// ---------- LayerNorm over C=1024, fp32 out (+ optional bf16 copy) ----------
template<bool DUAL>
__global__ __launch_bounds__(256)
void ln_k(const float* __restrict__ in, const float* __restrict__ w,
          const float* __restrict__ b, float* __restrict__ out,
          unsigned short* __restrict__ out_bf)
{
  __shared__ float red[8];
  const int row = blockIdx.x, tid = threadIdx.x;
  float4 v = *(const float4*)(in + (size_t)row * C_ + tid * 4);
  float s = v.x + v.y + v.z + v.w;
  #pragma unroll
  for (int off = 32; off > 0; off >>= 1) s += __shfl_down(s, off, 64);
  if ((tid & 63) == 0) red[tid >> 6] = s;
  __syncthreads();
  const float mu = (red[0] + red[1] + red[2] + red[3]) * (1.f / C_);
  const float dx = v.x - mu, dy = v.y - mu, dz = v.z - mu, dw = v.w - mu;
  float ss = dx*dx + dy*dy + dz*dz + dw*dw;
  #pragma unroll
  for (int off = 32; off > 0; off >>= 1) ss += __shfl_down(ss, off, 64);
  if ((tid & 63) == 0) red[4 + (tid >> 6)] = ss;
  __syncthreads();
  const float rinv = rsqrtf((red[4] + red[5] + red[6] + red[7]) * (1.f / C_) + 1e-5f);
  float4 wv = *(const float4*)(w + tid * 4);
  float4 bv = *(const float4*)(b + tid * 4);
  float4 o;
  o.x = dx * rinv * wv.x + bv.x;
  o.y = dy * rinv * wv.y + bv.y;
  o.z = dz * rinv * wv.z + bv.z;
  o.w = dw * rinv * wv.w + bv.w;
  *(float4*)(out + (size_t)row * C_ + tid * 4) = o;
  if constexpr (DUAL) {
    ushort4 o4; o4.x = f2bf(o.x); o4.y = f2bf(o.y); o4.z = f2bf(o.z); o4.w = f2bf(o.w);
    *(ushort4*)(out_bf + (size_t)row * C_ + tid * 4) = o4;
  }
}

// ---------- fused: sum NS split-K partials + residual, then LayerNorm ----------
template<int NS>
__global__ __launch_bounds__(256)
void ln_red(const float* __restrict__ p, const float* __restrict__ resid,
            const float* __restrict__ w, const float* __restrict__ b,
            float* __restrict__ out)
{
  __shared__ float red[8];
  const int row = blockIdx.x, tid = threadIdx.x;
  const size_t off = (size_t)row * C_ + tid * 4;
  const size_t st = (size_t)M_ * C_;
  float4 v = *(const float4*)(p + off);
  #pragma unroll
  for (int i = 1; i < NS; i++) {
    float4 vi = *(const float4*)(p + i * st + off);
    v.x += vi.x; v.y += vi.y; v.z += vi.z; v.w += vi.w;
  }
  float4 rr = *(const float4*)(resid + off);
  v.x += rr.x; v.y += rr.y; v.z += rr.z; v.w += rr.w;
  float s = v.x + v.y + v.z + v.w;
  #pragma unroll
  for (int o = 32; o > 0; o >>= 1) s += __shfl_down(s, o, 64);
  if ((tid & 63) == 0) red[tid >> 6] = s;
  __syncthreads();
  const float mu = (red[0] + red[1] + red[2] + red[3]) * (1.f / C_);
  const float dx = v.x - mu, dy = v.y - mu, dz = v.z - mu, dw = v.w - mu;
  float ss = dx*dx + dy*dy + dz*dz + dw*dw;
  #pragma unroll
  for (int o = 32; o > 0; o >>= 1) ss += __shfl_down(ss, o, 64);
  if ((tid & 63) == 0) red[4 + (tid >> 6)] = ss;
  __syncthreads();
  const float rinv = rsqrtf((red[4] + red[5] + red[6] + red[7]) * (1.f / C_) + 1e-5f);
  float4 wv = *(const float4*)(w + tid * 4);
  float4 bv = *(const float4*)(b + tid * 4);
  float4 o;
  o.x = dx * rinv * wv.x + bv.x;
  o.y = dy * rinv * wv.y + bv.y;
  o.z = dz * rinv * wv.z + bv.z;
  o.w = dw * rinv * wv.w + bv.w;
  *(float4*)(out + off) = o;
}

extern "C" void kernel_launch(void* const* d_in, const int* in_sizes, int n_in,
                              void* d_out, int out_size, void* d_ws, size_t ws_size,
                              hipStream_t stream)
{
  const float* x       = (const float*)d_in[0];
  const float* y       = (const float*)d_in[1];
  const float* W_attn  = (const float*)d_in[2];
  const float* b_attn  = (const float*)d_in[3];
  const float* W_proj  = (const float*)d_in[4];
  const float* b_proj  = (const float*)d_in[5];
  const float* ln_w    = (const float*)d_in[6];
  const float* ln_b    = (const float*)d_in[7];
  const float* W_en    = (const float*)d_in[8];
  const float* b_en    = (const float*)d_in[9];
  const float* W_q     = (const float*)d_in[10];
  const float* b_q     = (const float*)d_in[11];
  const float* W_cproj = (const float*)d_in[12];
  const float* b_cproj = (const float*)d_in[13];
  const float* ln1_w   = (const float*)d_in[14];
  const float* ln1_b   = (const float*)d_in[15];
  const float* ln2_w   = (const float*)d_in[16];
  const float* ln2_b   = (const float*)d_in[17];
  const float* W_d1    = (const float*)d_in[18];
  const float* b_d1    = (const float*)d_in[19];
  const float* W_d2    = (const float*)d_in[20];
  const float* b_d2    = (const float*)d_in[21];

  char* wsb = (char*)d_ws;
  const size_t MB = 1024 * 1024;
  unsigned short* wt_attn  = (unsigned short*)(wsb + 0 * MB);
  unsigned short* wt_proj  = (unsigned short*)(wsb + 6 * MB);
  unsigned short* wt_en    = (unsigned short*)(wsb + 8 * MB);
  unsigned short* wt_q     = (unsigned short*)(wsb + 12 * MB);
  unsigned short* wt_cproj = (unsigned short*)(wsb + 14 * MB);
  unsigned short* wt_d1    = (unsigned short*)(wsb + 16 * MB);
  unsigned short* wt_d2    = (unsigned short*)(wsb + 24 * MB);
  unsigned short* y_bf     = (unsigned short*)(wsb + 32 * MB);
  unsigned short* yb_bf    = y_bf;
  unsigned short* x_bf     = (unsigned short*)(wsb + 40 * MB);
  unsigned short* xin_bf   = x_bf;
  unsigned short* qkvb     = (unsigned short*)(wsb + 48 * MB);   // [M][2048] Q|K
  unsigned short* vt1      = (unsigned short*)(wsb + 64 * MB);   // [B*16][64][T]
  unsigned short* kvK      = (unsigned short*)(wsb + 72 * MB);   // [M][1024]
  unsigned short* vt2      = (unsigned short*)(wsb + 80 * MB);
  unsigned short* q2b      = (unsigned short*)(wsb + 88 * MB);
  unsigned short* o1_bf    = (unsigned short*)(wsb + 96 * MB);
  unsigned short* o2_bf    = o1_bf;
  float*          yb       = (float*)(wsb + 104 * MB);
  float*          xin      = (float*)(wsb + 120 * MB);
  unsigned short* h_bf     = (unsigned short*)(wsb + 136 * MB);
  float*          part     = (float*)(wsb + 48 * MB);  // step-11 partials, 2x16MB (48..80MB all dead by step 11)
  float*          z        = (float*)d_out;

  const dim3 b256(256), b128(128);

  // --- prep ---
  conv_f2b<<<dim3(M_*C_/1024), b256, 0, stream>>>(y, y_bf);
  conv_f2b<<<dim3(M_*C_/1024), b256, 0, stream>>>(x, x_bf);
  transpose_conv<<<dim3(96, 32),  b256, 0, stream>>>(W_attn,  wt_attn,  C_, 3*C_);
  transpose_conv<<<dim3(32, 32),  b256, 0, stream>>>(W_proj,  wt_proj,  C_, C_);
  transpose_conv<<<dim3(64, 32),  b256, 0, stream>>>(W_en,    wt_en,    C_, 2*C_);
  transpose_conv<<<dim3(32, 32),  b256, 0, stream>>>(W_q,     wt_q,     C_, C_);
  transpose_conv<<<dim3(32, 32),  b256, 0, stream>>>(W_cproj, wt_cproj, C_, C_);
  transpose_conv<<<dim3(128, 32), b256, 0, stream>>>(W_d1,    wt_d1,    C_, DFF_);
  transpose_conv<<<dim3(32, 128), b256, 0, stream>>>(W_d2,    wt_d2,    DFF_, C_);

  // 1. qkv = y @ W_attn + b_attn -> Q|K bf16 [M][2048], V -> vt1 (transposed)
  mgemm<128, false, true><<<dim3(24, 32), b256, 0, stream>>>(y_bf, wt_attn, b_attn, nullptr, qkvb, 3*C_, C_, 2048, 2048, vt1, C_);
  // 2. self-attention -> o1 (bf16)
  mattn<<<dim3(T_/64, B_*H_), b256, 0, stream>>>(qkvb, 2048, qkvb + 1024, 2048, vt1, o1_bf);
  // 3. y1 = o1 @ W_proj + b_proj + y  (fp32)  [TM=64 dbuf: measured-best for this shape]
  mgemm<64, true, false><<<dim3(8, 64), b128, 0, stream>>>(o1_bf, wt_proj, b_proj, y, yb, C_, C_, C_, C_, nullptr, C_);
  // 4. y2 = LN(y1) in-place, dual out
  ln_k<true><<<dim3(M_), b256, 0, stream>>>(yb, ln_w, ln_b, yb, yb_bf);
  // 5. kv = x @ W_en + b_en -> K bf16 [M][1024], V -> vt2 (transposed)
  mgemm<128, false, true><<<dim3(16, 32), b256, 0, stream>>>(x_bf, wt_en, b_en, nullptr, kvK, 2*C_, C_, 1024, 1024, vt2, C_);
  // 6. q2 = y2 @ W_q + b_q (bf16)  [TM=64 dbuf]
  mgemm<64, false, true><<<dim3(8, 64), b128, 0, stream>>>(yb_bf, wt_q, b_q, nullptr, q2b, C_, C_, 1024, C_, nullptr, C_);
  // 7. cross-attention -> o2 (bf16)
  mattn<<<dim3(T_/64, B_*H_), b256, 0, stream>>>(q2b, 1024, kvK, 1024, vt2, o2_bf);
  // 8. y3 = o2 @ W_cproj + b_cproj + y2  (fp32 -> xin)  [TM=64 dbuf]
  mgemm<64, true, false><<<dim3(8, 64), b128, 0, stream>>>(o2_bf, wt_cproj, b_cproj, yb, xin, C_, C_, C_, C_, nullptr, C_);
  // 9. x_in = LN(y3) in-place, dual out
  ln_k<true><<<dim3(M_), b256, 0, stream>>>(xin, ln1_w, ln1_b, xin, xin_bf);
  // 10. h = x_in @ W_d1 + b_d1  (bf16)
  mgemm<128, false, true><<<dim3(32, 32), b256, 0, stream>>>(xin_bf, wt_d1, b_d1, nullptr, h_bf, DFF_, C_, DFF_, DFF_, nullptr, C_);
  // 11. z-partials = h @ W_d2 (+b_d2 on z==0), split-K=2 over DFF (TM=128)
  mgemm<128, false, false><<<dim3(8, 32, 2), b256, 0, stream>>>(h_bf, wt_d2, b_d2, nullptr, part, C_, DFF_, C_, C_, nullptr, 2048);
  // 12. out = LN(p0+p1 + xin)  -> d_out
  ln_red<2><<<dim3(M_), b256, 0, stream>>>(part, xin, ln2_w, ln2_b, z);
}